// Round 1
// 380.005 us; speedup vs baseline: 1.1091x; 1.1091x over previous
//
#include <hip/hip_runtime.h>
#include <hip/hip_bf16.h>
#include <math.h>

typedef __hip_bfloat16 bf16;
typedef __attribute__((ext_vector_type(8))) short short8;
typedef __attribute__((ext_vector_type(4))) float floatx4;

#define B_   2
#define S_   2048
#define D_   1024
#define H_   16
#define DH_  64
#define BS_  4096   // B_*S_
#define D3_  3072   // 3*D_
#define DF_  4096   // 4*D_

__device__ __forceinline__ float tof(float v) { return v; }
__device__ __forceinline__ float tof(bf16 v) { return __bfloat162float(v); }
__device__ __forceinline__ void stf(float* p, size_t i, float v) { p[i] = v; }
__device__ __forceinline__ void stf(bf16* p, size_t i, float v) { p[i] = __float2bfloat16(v); }

// async global->LDS 16B copy: lane's data lands at readfirstlane(lds)+lane*16
__device__ __forceinline__ void gload_lds16(const bf16* g, bf16* l) {
  __builtin_amdgcn_global_load_lds(
      (const __attribute__((address_space(1))) unsigned int*)g,
      (__attribute__((address_space(3))) unsigned int*)l, 16, 0, 0);
}

#define VMCNT(n) asm volatile("s_waitcnt vmcnt(" #n ")" ::: "memory")

// ---------------------------------------------------------------------------
// fp32 -> bf16 weight conversion (vectorized x4)
// ---------------------------------------------------------------------------
__global__ __launch_bounds__(256) void cvt_f32_bf16(
    const float* __restrict__ in, bf16* __restrict__ out, int n4) {
  int i = blockIdx.x * 256 + threadIdx.x;
  if (i >= n4) return;
  float4 v = ((const float4*)in)[i];
  bf16 o[4] = {__float2bfloat16(v.x), __float2bfloat16(v.y),
               __float2bfloat16(v.z), __float2bfloat16(v.w)};
  ((ulong1*)out)[i] = *(ulong1*)o;
}

// ---------------------------------------------------------------------------
// Fused convert: w_qkv fp32->bf16 with ROW PERMUTE n=d*48+z*16+h -> n2=
// z*1024+h*64+d (so QKV gemm emits [b,s][z,h,d] and no extract pass is
// needed), plus plain convert of w_o. 4 els/thread, both sides coalesced.
// ---------------------------------------------------------------------------
__global__ __launch_bounds__(256) void cvt_qkv_o(
    const float* __restrict__ wqkv, const float* __restrict__ wo,
    bf16* __restrict__ wqb, bf16* __restrict__ wob) {
  const int g = blockIdx.x * 256 + threadIdx.x;  // 4-el group
  if (g < 786432) {                              // 3072*1024/4 : permute+cvt
    const int n2 = g >> 8;                       // dest row (z,h,d)
    const int col = (g & 255) * 4;
    const int z = n2 >> 10, hh = (n2 >> 6) & 15, d = n2 & 63;
    const int n = d * 48 + z * 16 + hh;          // src row
    float4 v = *(const float4*)(wqkv + (size_t)n * 1024 + col);
    bf16 o[4] = {__float2bfloat16(v.x), __float2bfloat16(v.y),
                 __float2bfloat16(v.z), __float2bfloat16(v.w)};
    *(unsigned long long*)(wqb + (size_t)n2 * 1024 + col) =
        *(unsigned long long*)o;
  } else {
    const int g2 = g - 786432;                   // w_o: 1024*1024/4 groups
    float4 v = ((const float4*)wo)[g2];
    bf16 o[4] = {__float2bfloat16(v.x), __float2bfloat16(v.y),
                 __float2bfloat16(v.z), __float2bfloat16(v.w)};
    ((unsigned long long*)wob)[g2] = *(unsigned long long*)o;
  }
}

// ---------------------------------------------------------------------------
// LayerNorm (optionally fused with residual add): one block per row of D_=1024
// ---------------------------------------------------------------------------
template <bool FUSE, typename TA, typename TS>
__global__ __launch_bounds__(256) void resid_ln_kernel(
    const TA* __restrict__ a, const TS* __restrict__ skip,
    const float* __restrict__ w, const float* __restrict__ bias,
    bf16* __restrict__ x2, bf16* __restrict__ hout, float st, float s1t) {
  const int row = blockIdx.x;
  const int tid = threadIdx.x;
  const int base = tid * 4;
  const size_t roff = (size_t)row * D_;

  float xv[4];
#pragma unroll
  for (int i = 0; i < 4; i++) {
    float v = tof(a[roff + base + i]);
    if (FUSE) v = st * v + s1t * tof(skip[roff + base + i]);
    xv[i] = v;
  }
  if (FUSE) {
#pragma unroll
    for (int i = 0; i < 4; i++) x2[roff + base + i] = __float2bfloat16(xv[i]);
  }

  float ls = 0.f, lq = 0.f;
#pragma unroll
  for (int i = 0; i < 4; i++) { ls += xv[i]; lq += xv[i] * xv[i]; }

  __shared__ float ssum[256];
  __shared__ float ssq[256];
  ssum[tid] = ls; ssq[tid] = lq;
  __syncthreads();
  for (int off = 128; off > 0; off >>= 1) {
    if (tid < off) { ssum[tid] += ssum[tid + off]; ssq[tid] += ssq[tid + off]; }
    __syncthreads();
  }
  const float mean = ssum[0] * (1.0f / D_);
  const float var  = ssq[0] * (1.0f / D_) - mean * mean;
  const float rstd = rsqrtf(var + 1e-5f);

#pragma unroll
  for (int i = 0; i < 4; i++) {
    float v = (xv[i] - mean) * rstd * w[base + i] + bias[base + i];
    hout[roff + base + i] = __float2bfloat16(v);
  }
}

// ---------------------------------------------------------------------------
// MFMA GEMM (legacy 128x128 / 64x128, 1-phase): kept for N=1024 GEMMs
// (out-proj, FFN2) whose 256^2 grids would underfill the chip.
// ---------------------------------------------------------------------------
template <int EPI, int BM, int BN, typename TC>
__global__ __launch_bounds__(256) void gemm_mfma(
    const bf16* __restrict__ A, const bf16* __restrict__ Bw,
    TC* __restrict__ C, int M, int N, int K, float scale,
    const float* __restrict__ bias, const bf16* __restrict__ resid,
    float st, float s1t) {
  constexpr int FI = BM / 32;
  constexpr int FJ = BN / 32;
  constexpr int NA = BM * 8 / 256;
  constexpr int NB = BN * 8 / 256;

  __shared__ __align__(16) bf16 As[BM][64];
  __shared__ __align__(16) bf16 Bs[BN][64];

  const int tid = threadIdx.x;
  const int lane = tid & 63;
  const int w = tid >> 6;
  const int wm = (w >> 1) * (BM / 2);
  const int wn = (w & 1) * (BN / 2);
  const int quad = lane >> 4;
  const int l16 = lane & 15;
  const int bm = blockIdx.y * BM, bn = blockIdx.x * BN;

  floatx4 acc[FI][FJ];
#pragma unroll
  for (int i = 0; i < FI; i++)
#pragma unroll
    for (int j = 0; j < FJ; j++) acc[i][j] = {0.f, 0.f, 0.f, 0.f};

  const bf16* Ap[NA];
  bf16* lA[NA];
#pragma unroll
  for (int i = 0; i < NA; i++) {
    const int c = tid + i * 256;
    Ap[i] = A + (size_t)(bm + (c >> 3)) * K + (c & 7) * 8;
    lA[i] = (bf16*)As + (size_t)c * 8;
  }
  const bf16* Bp[NB];
  bf16* lB[NB];
#pragma unroll
  for (int i = 0; i < NB; i++) {
    const int c = tid + i * 256;
    Bp[i] = Bw + (size_t)(bn + (c >> 3)) * K + (c & 7) * 8;
    lB[i] = (bf16*)Bs + (size_t)c * 8;
  }

  for (int k0 = 0; k0 < K; k0 += 64) {
    __syncthreads();
#pragma unroll
    for (int i = 0; i < NA; i++) gload_lds16(Ap[i] + k0, lA[i]);
#pragma unroll
    for (int i = 0; i < NB; i++) gload_lds16(Bp[i] + k0, lB[i]);
    __syncthreads();

#pragma unroll
    for (int kc = 0; kc < 2; kc++) {
      short8 af[FI], bf[FJ];
#pragma unroll
      for (int f = 0; f < FI; f++)
        af[f] = *(const short8*)&As[wm + f * 16 + l16][kc * 32 + quad * 8];
#pragma unroll
      for (int f = 0; f < FJ; f++)
        bf[f] = *(const short8*)&Bs[wn + f * 16 + l16][kc * 32 + quad * 8];
#pragma unroll
      for (int fi = 0; fi < FI; fi++)
#pragma unroll
        for (int fj = 0; fj < FJ; fj++)
          acc[fi][fj] = __builtin_amdgcn_mfma_f32_16x16x32_bf16(
              af[fi], bf[fj], acc[fi][fj], 0, 0, 0);
    }
  }

#pragma unroll
  for (int fi = 0; fi < FI; fi++) {
#pragma unroll
    for (int fj = 0; fj < FJ; fj++) {
      const int col = bn + wn + fj * 16 + l16;
#pragma unroll
      for (int r = 0; r < 4; r++) {
        const int row = bm + wm + fi * 16 + quad * 4 + r;
        float v = acc[fi][fj][r];
        if (EPI == 0) {
          v *= scale;
        } else if (EPI == 1) {
          v = (v + bias[col]) * scale;
          v = 0.5f * v * (1.0f + erff(v * 0.70710678118654752f)) * st;
        } else {
          v = (v + bias[col]) * scale;
          v = st * v + s1t * __bfloat162float(resid[(size_t)row * N + col]);
        }
        stf(C, (size_t)row * N + col, v);
      }
    }
  }
}

// ---------------------------------------------------------------------------
// 256x256 8-phase MFMA GEMM (T1+T2+T3+T4+T5 stack, plain-HIP port of the
// m201 template). 512 threads = 8 waves (2M x 4N); per-wave C = 128x64;
// BK=64; LDS = 128 KiB (2 dbuf x {A,B} x 256x64 bf16).
//
// Chunk layout (per buffer, per operand, 2 chunks of 128 rows x 64 k):
//   A chunk h: rows {wm*128 + h*64 .. +63} for wm in {0,1}  (phase-aligned)
//   B chunk bh: rows {wn*64 + bh*32 .. +31} for wn in {0..3}
// Chunk stage order per tile t (issued during tile t-1's phases 1..4):
//   C0=A(h0), C1=B(bh0), C2=A(h1), C3=B(bh1)
// Phase p consumption of tile t: p1:{C0,C1} p2:{C3} p3:{C2} p4:{C1 re-read}
// Waits (counted, never 0 in steady loop):
//   end p1: vmcnt(2)  -> C3(t) landed  (only C0(t+1) may be in flight)
//   end p4: vmcnt(4)  -> C0,C1(t+1) landed (C2,C3(t+1) in flight)
// Bank-conflict fix: rows are 128B -> granule ^= (row&7) XOR swizzle, applied
// on the global SOURCE address (gload_lds dest must stay linear, rule 21)
// and on the ds_read address (same involution).
// ---------------------------------------------------------------------------
template <int EPI>
__global__ __launch_bounds__(512, 2) void gemm_mfma256(
    const bf16* __restrict__ A, const bf16* __restrict__ Bw,
    bf16* __restrict__ C, int M, int N, int K, float scale,
    const float* __restrict__ bias, float st) {
  __shared__ __align__(16) bf16 As[2][2][128][64];  // [buf][chunk h][row][k]
  __shared__ __align__(16) bf16 Bs[2][2][128][64];  // [buf][chunk bh][row][k]

  const int tid = threadIdx.x;
  const int lane = tid & 63;
  const int w = tid >> 6;          // 0..7
  const int wm = w >> 2;           // 0..1  (M half)
  const int wn = w & 3;            // 0..3  (N quarter)
  const int quad = lane >> 4;
  const int l16 = lane & 15;

  // T1: XCD-aware block swizzle (nwg % 8 == 0 for both call sites)
  const int nbx = N >> 8;
  const int nwg = nbx * (M >> 8);
  int bid = blockIdx.x;
  bid = (bid & 7) * (nwg >> 3) + (bid >> 3);
  const size_t bm = (size_t)(bid / nbx) * 256;
  const size_t bn = (size_t)(bid % nbx) * 256;

  // staging: chunk c in {0:A.h0, 1:B.bh0, 2:A.h1, 3:B.bh1}, 2 x 16B per thread
  const bf16* gsrc[4][2];
  bf16* ldsp[4][2];
#pragma unroll
  for (int i = 0; i < 2; i++) {
    const int G = tid + i * 512;               // granule 0..1023 within chunk
    const int cr = G >> 3;                     // chunk row 0..127
    const int gs8 = ((G & 7) ^ (cr & 7)) * 8;  // pre-swizzled source column
    const int ra = ((cr >> 6) << 7) + (cr & 63);       // A: + h*64
    const int rb = ((cr >> 5) << 6) + (cr & 31);       // B: + bh*32
    gsrc[0][i] = A  + (bm + ra) * (size_t)K + gs8;
    gsrc[2][i] = A  + (bm + ra + 64) * (size_t)K + gs8;
    gsrc[1][i] = Bw + (bn + rb) * (size_t)K + gs8;
    gsrc[3][i] = Bw + (bn + rb + 32) * (size_t)K + gs8;
    ldsp[0][i] = &As[0][0][0][0] + G * 8;
    ldsp[2][i] = &As[0][1][0][0] + G * 8;
    ldsp[1][i] = &Bs[0][0][0][0] + G * 8;
    ldsp[3][i] = &Bs[0][1][0][0] + G * 8;
  }

  auto STAGE = [&](int c, int tn) {
    const int boff = (tn & 1) * 16384;  // els between buf0/buf1
    gload_lds16(gsrc[c][0] + (size_t)tn * 64, ldsp[c][0] + boff);
    gload_lds16(gsrc[c][1] + (size_t)tn * 64, ldsp[c][1] + boff);
  };

  // swizzled k-granule offsets for ds_read (kc=0 -> quad, kc=1 -> 4+quad)
  const int ksw0 = (quad ^ (l16 & 7)) * 8;
  const int ksw1 = ((4 + quad) ^ (l16 & 7)) * 8;

  floatx4 acc[8][4];
#pragma unroll
  for (int i = 0; i < 8; i++)
#pragma unroll
    for (int j = 0; j < 4; j++) acc[i][j] = {0.f, 0.f, 0.f, 0.f};

  short8 af[4][2], bv[2][2];

  auto READ_A = [&](int b, int h) {
#pragma unroll
    for (int mf = 0; mf < 4; mf++) {
      const bf16* p = &As[b][h][wm * 64 + mf * 16 + l16][0];
      af[mf][0] = *(const short8*)(p + ksw0);
      af[mf][1] = *(const short8*)(p + ksw1);
    }
  };
  auto READ_B = [&](int b, int bh) {
#pragma unroll
    for (int nf = 0; nf < 2; nf++) {
      const bf16* p = &Bs[b][bh][wn * 32 + nf * 16 + l16][0];
      bv[nf][0] = *(const short8*)(p + ksw0);
      bv[nf][1] = *(const short8*)(p + ksw1);
    }
  };
  auto MFMA16 = [&](int mb, int nb) {
#pragma unroll
    for (int mf = 0; mf < 4; mf++)
#pragma unroll
      for (int nf = 0; nf < 2; nf++) {
        floatx4 c = acc[mb + mf][nb + nf];
        c = __builtin_amdgcn_mfma_f32_16x16x32_bf16(af[mf][0], bv[nf][0], c, 0, 0, 0);
        c = __builtin_amdgcn_mfma_f32_16x16x32_bf16(af[mf][1], bv[nf][1], c, 0, 0, 0);
        acc[mb + mf][nb + nf] = c;
      }
  };

  // prologue: full tile 0
  STAGE(0, 0); STAGE(1, 0); STAGE(2, 0); STAGE(3, 0);
  VMCNT(4);
  __builtin_amdgcn_s_barrier();
  __builtin_amdgcn_sched_barrier(0);

  const int NT = K >> 6;
#pragma unroll 1
  for (int t = 0; t < NT; t++) {
    const int b = t & 1;
    const bool nl = (t + 1 < NT);
    // ---- phase 1: Q00 (A.h0 x B.bh0) ----
    READ_A(b, 0);
    READ_B(b, 0);
    if (nl) STAGE(0, t + 1);
    __builtin_amdgcn_s_barrier();
    __builtin_amdgcn_sched_barrier(0);
    __builtin_amdgcn_s_setprio(1);
    MFMA16(0, 0);
    __builtin_amdgcn_s_setprio(0);
    if (nl) { VMCNT(2); } else { VMCNT(0); }
    __builtin_amdgcn_s_barrier();
    __builtin_amdgcn_sched_barrier(0);
    // ---- phase 2: Q01 (A.h0 regs x B.bh1) ----
    READ_B(b, 1);
    if (nl) STAGE(1, t + 1);
    __builtin_amdgcn_s_barrier();
    __builtin_amdgcn_sched_barrier(0);
    __builtin_amdgcn_s_setprio(1);
    MFMA16(0, 2);
    __builtin_amdgcn_s_setprio(0);
    __builtin_amdgcn_s_barrier();
    __builtin_amdgcn_sched_barrier(0);
    // ---- phase 3: Q11 (A.h1 x B.bh1 regs) ----
    READ_A(b, 1);
    if (nl) STAGE(2, t + 1);
    __builtin_amdgcn_s_barrier();
    __builtin_amdgcn_sched_barrier(0);
    __builtin_amdgcn_s_setprio(1);
    MFMA16(4, 2);
    __builtin_amdgcn_s_setprio(0);
    __builtin_amdgcn_s_barrier();
    __builtin_amdgcn_sched_barrier(0);
    // ---- phase 4: Q10 (A.h1 regs x B.bh0 re-read) ----
    READ_B(b, 0);
    if (nl) STAGE(3, t + 1);
    __builtin_amdgcn_s_barrier();
    __builtin_amdgcn_sched_barrier(0);
    __builtin_amdgcn_s_setprio(1);
    MFMA16(4, 0);
    __builtin_amdgcn_s_setprio(0);
    if (nl) { VMCNT(4); } else { VMCNT(0); }
    __builtin_amdgcn_s_barrier();
    __builtin_amdgcn_sched_barrier(0);
  }

  // epilogue
  float bias4[4];
  if (EPI == 1) {
#pragma unroll
    for (int j = 0; j < 4; j++) bias4[j] = bias[bn + wn * 64 + j * 16 + l16];
  }
#pragma unroll
  for (int mi = 0; mi < 8; mi++) {
    const size_t r0 = bm + wm * 128 + (mi >> 2) * 64 + (mi & 3) * 16 + quad * 4;
#pragma unroll
    for (int r = 0; r < 4; r++) {
      bf16* Cr = C + (r0 + r) * (size_t)N + bn + wn * 64 + l16;
#pragma unroll
      for (int j = 0; j < 4; j++) {
        float v = acc[mi][j][r];
        if (EPI == 0) {
          v *= scale;
        } else {
          // GELU (tanh form) via raw v_exp_f32 / v_rcp_f32; |err| ~1e-3 abs,
          // well under bf16 quantization + current absmax headroom.
          float u = (v + bias4[j]) * scale;
          float tt = u * (0.7978845608f + 0.0356774081f * u * u);
          float e = __builtin_amdgcn_exp2f(tt * 2.8853900818f);  // exp(2*tt)
          float th = 1.0f - 2.0f * __builtin_amdgcn_rcpf(e + 1.0f);
          v = 0.5f * u * (1.0f + th) * st;
        }
        Cr[j * 16] = __float2bfloat16(v);
      }
    }
  }
}

// ---------------------------------------------------------------------------
// MFMA flash attention, S^T scheme, 512 threads = 8 waves, QT=128, KT=64.
// Reads Q/K/V DIRECTLY from the head-major qkv buffer [b,s][z,h,d]:
// base = qkv + b*S*D3 + h*64 + z*1024, row stride D3 (=3072).
// Double-buffered K/V LDS + register prefetch (one barrier per iter).
// ---------------------------------------------------------------------------
__global__ __launch_bounds__(512) void flash_attn_mfma(
    const bf16* __restrict__ qkv, bf16* __restrict__ att,
    float sc2, float out_scale) {
  const int qb = blockIdx.x * 128;
  const int h = blockIdx.y, b = blockIdx.z;
  const int tid = threadIdx.x;
  const int lane = tid & 63;
  const int wv = tid >> 6;           // 0..7
  const int quad = lane >> 4;
  const int l16 = lane & 15;

  __shared__ __align__(16) bf16 Ks[2][64][72];
  __shared__ __align__(16) bf16 Vt[2][64][72];  // Vt[d][j] = V[j][d]
  __shared__ __align__(16) bf16 Ps[128][68];    // P [query][key]

  const bf16* Qb_ = qkv + (size_t)b * S_ * D3_ + h * DH_;
  const bf16* Kb_ = Qb_ + 1024;
  const bf16* Vb_ = Qb_ + 2048;

  // Q as B-operand frag: queries qb + wv*16 + l16
  short8 bq0, bq1;
  {
    const bf16* qrow = Qb_ + (size_t)(qb + wv * 16 + l16) * D3_ + quad * 8;
    bq0 = *(const short8*)(qrow);
    bq1 = *(const short8*)(qrow + 32);
  }

  float m_r = -1e30f, l_r = 0.f;
  floatx4 o[4];
#pragma unroll
  for (int fd = 0; fd < 4; fd++) o[fd] = {0.f, 0.f, 0.f, 0.f};

  // staging (512 threads): K chunk = 1 x 16B; V = 1 uint4 -> 8 b16 scatters
  const int kr = tid >> 3, ko = (tid & 7) * 8;
  const int vj = tid & 63, vd = (tid >> 6) * 8;

  // prologue: prefetch tile 0 into registers
  uint4 kreg = *(const uint4*)(Kb_ + (size_t)kr * D3_ + ko);
  uint4 vreg = *(const uint4*)(Vb_ + (size_t)vj * D3_ + vd);

  int cur = 0;
  for (int t = 0; t < S_ / 64; t++) {
    // commit prefetched tile into buf[cur]
    *(uint4*)&Ks[cur][kr][ko] = kreg;
    {
      bf16 tmp[8];
      *(uint4*)tmp = vreg;
#pragma unroll
      for (int e = 0; e < 8; e++) Vt[cur][vd + e][vj] = tmp[e];
    }
    __syncthreads();

    // prefetch tile t+1 (clamped; redundant reload on last iter)
    {
      const int tn = (t + 1 < S_ / 64) ? t + 1 : t;
      kreg = *(const uint4*)(Kb_ + (size_t)(tn * 64 + kr) * D3_ + ko);
      vreg = *(const uint4*)(Vb_ + (size_t)(tn * 64 + vj) * D3_ + vd);
    }

    // S^T = K Q^T : lane holds keys fk*16 + quad*4 + r for query wv*16+l16
    float st[4][4];
#pragma unroll
    for (int fk = 0; fk < 4; fk++) {
      short8 ak0 = *(const short8*)&Ks[cur][fk * 16 + l16][quad * 8];
      short8 ak1 = *(const short8*)&Ks[cur][fk * 16 + l16][32 + quad * 8];
      floatx4 acc = {0.f, 0.f, 0.f, 0.f};
      acc = __builtin_amdgcn_mfma_f32_16x16x32_bf16(ak0, bq0, acc, 0, 0, 0);
      acc = __builtin_amdgcn_mfma_f32_16x16x32_bf16(ak1, bq1, acc, 0, 0, 0);
#pragma unroll
      for (int r = 0; r < 4; r++) st[fk][r] = acc[r] * sc2;
    }

    // online softmax per query (in-lane over 16 keys, then xor16/32)
    float mx = st[0][0];
#pragma unroll
    for (int fk = 0; fk < 4; fk++)
#pragma unroll
      for (int r = 0; r < 4; r++) mx = fmaxf(mx, st[fk][r]);
    mx = fmaxf(mx, __shfl_xor(mx, 16));
    mx = fmaxf(mx, __shfl_xor(mx, 32));
    const float mn = fmaxf(m_r, mx);
    const float alpha = exp2f(m_r - mn);
    m_r = mn;
    float rs = 0.f;
#pragma unroll
    for (int fk = 0; fk < 4; fk++) {
      bf16 pk[4];
#pragma unroll
      for (int r = 0; r < 4; r++) {
        const float p = exp2f(st[fk][r] - mn);
        rs += p;
        pk[r] = __float2bfloat16(p);
      }
      *(uint2*)&Ps[wv * 16 + l16][fk * 16 + quad * 4] = *(uint2*)pk;
    }
    rs += __shfl_xor(rs, 16);
    rs += __shfl_xor(rs, 32);
    l_r = alpha * l_r + rs;

    // rescale O: row r of O frag = query quad*4+r; fetch its alpha
#pragma unroll
    for (int r = 0; r < 4; r++) {
      const float a = __shfl(alpha, quad * 20 + r, 64);
#pragma unroll
      for (int fd = 0; fd < 4; fd++) o[fd][r] *= a;
    }

    // O += P V
    short8 ap0 = *(const short8*)&Ps[wv * 16 + l16][quad * 8];
    short8 ap1 = *(const short8*)&Ps[wv * 16 + l16][32 + quad * 8];
#pragma unroll
    for (int fd = 0; fd < 4; fd++) {
      short8 bv0 = *(const short8*)&Vt[cur][fd * 16 + l16][quad * 8];
      short8 bv1 = *(const short8*)&Vt[cur][fd * 16 + l16][32 + quad * 8];
      o[fd] = __builtin_amdgcn_mfma_f32_16x16x32_bf16(ap0, bv0, o[fd], 0, 0, 0);
      o[fd] = __builtin_amdgcn_mfma_f32_16x16x32_bf16(ap1, bv1, o[fd], 0, 0, 0);
    }

    cur ^= 1;
  }

  // epilogue: O row -> query wv*16 + quad*4 + r; its l via shfl
#pragma unroll
  for (int r = 0; r < 4; r++) {
    const float lq = __shfl(l_r, quad * 20 + r, 64);
    const float sc = out_scale / lq;
    const size_t base =
        ((size_t)(b * S_ + qb + wv * 16 + quad * 4 + r)) * D_ + h * DH_;
#pragma unroll
    for (int fd = 0; fd < 4; fd++)
      att[base + fd * 16 + l16] = __float2bfloat16(o[fd][r] * sc);
  }
}

// ---------------------------------------------------------------------------
extern "C" void kernel_launch(void* const* d_in, const int* in_sizes, int n_in,
                              void* d_out, int out_size, void* d_ws, size_t ws_size,
                              hipStream_t stream) {
  const float* x     = (const float*)d_in[0];
  const float* w_qkv = (const float*)d_in[1];
  const float* w_o   = (const float*)d_in[2];
  const float* w1    = (const float*)d_in[3];
  const float* b1    = (const float*)d_in[4];
  const float* w2    = (const float*)d_in[5];
  const float* b2    = (const float*)d_in[6];
  const float* ln1w  = (const float*)d_in[7];
  const float* ln1b  = (const float*)d_in[8];
  const float* ln2w  = (const float*)d_in[9];
  const float* ln2b  = (const float*)d_in[10];
  float* out = (float*)d_out;
  bf16* ws  = (bf16*)d_ws;

  // workspace layout (bf16 els), liveness-audited, peak 29,360,128 els (58.7MB)
  // slots: 1 cvt_qo, 2 LN1, 3 QKVgemm, 4 flash, 5 Oproj, 6 LN2,
  //        6.5 cvt w1, 7 FFN1, 7.5 cvt w2, 8 FFN2
  bf16* h1       = ws;                 // [0,4.19M)      live 2->3
  bf16* att      = ws;                 //                live 4->5 (h1 dead)
  bf16* h2       = ws + 20971520;      // [20.97,25.17M) live 6->7
  bf16* wqb      = ws + 4194304;       // [4.19,7.34M)   live 1->3
  bf16* wob      = ws + 7340032;       // [7.34,8.39M)   live 1->5
  bf16* attn_out = ws + 8388608;       // [8.39,12.58M)  live 5->6
  bf16* qkv      = ws + 16777216;      // [16.78,29.36M) live 3->4
  bf16* w1b      = ws + 16777216;      // [16.78,20.97M) live 6.5->7 (qkv dead)
  bf16* w2b      = ws + 16777216;      // [16.78,20.97M) live 7.5->8 (w1b dead)
  bf16* x2       = ws + 25165824;      // [25.17,29.36M) live 6->8
  bf16* g        = ws;                 // [0,16.78M)     live 7->8 (all dead)

  const float MM_SCALE   = (float)pow((double)S_ * S_ * DH_, -1.0 / 6.0);
  const float SM_SCALE   = (float)((double)S_ / sqrt(1.31 * 1.65));
  const float GELU_SCALE = (float)pow(0.588 * 0.675, -0.5);
  const float SQRT_TAU   = (float)sqrt(0.2);
  const float SQRT_1MT   = (float)sqrt(0.8);
  const float LOG2E      = 1.4426950408889634f;
  const float qkv_scale  = (float)pow((double)D_ * D3_, -0.25);
  const float o_scale    = (float)pow((double)D_ * D_, -0.25);
  const float w1_scale   = (float)pow((double)D_ * DF_, -0.25);
  const float w2_scale   = (float)pow((double)DF_ * D_, -0.25);

  // 1. convert w_qkv (permuted) + w_o
  cvt_qkv_o<<<4096, 256, 0, stream>>>(w_qkv, w_o, wqb, wob);
  // 2. LN1
  resid_ln_kernel<false, float, float><<<BS_, 256, 0, stream>>>(
      x, nullptr, ln1w, ln1b, nullptr, h1, 0.f, 0.f);
  // 3. QKV gemm -> head-major qkv: 256^2 8-phase (grid 16*12=192)
  gemm_mfma256<0><<<dim3((BS_ / 256) * (D3_ / 256)), 512, 0, stream>>>(
      h1, wqb, qkv, BS_, D3_, D_, qkv_scale, nullptr, 0.f);
  // 4. MFMA flash attention (512 blocks x 8 waves), reads qkv directly
  flash_attn_mfma<<<dim3(S_ / 128, H_, B_), 512, 0, stream>>>(
      qkv, att, MM_SCALE * LOG2E, SM_SCALE * MM_SCALE);
  // 5. out-proj (BM=64 -> 512 blocks)
  gemm_mfma<0, 64, 128, bf16><<<dim3(D_ / 128, BS_ / 64), 256, 0, stream>>>(
      att, wob, attn_out, BS_, D_, D_, o_scale, nullptr, nullptr, 0.f, 0.f);
  // 6. residual + LN2
  resid_ln_kernel<true, bf16, float><<<BS_, 256, 0, stream>>>(
      attn_out, x, ln2w, ln2b, x2, h2, SQRT_TAU, SQRT_1MT);
  // 6.5 convert w1; 7. FFN1 + GELU: 256^2 8-phase (grid 16*16=256)
  cvt_f32_bf16<<<(DF_ * D_ / 4 + 255) / 256, 256, 0, stream>>>(w1, w1b, DF_ * D_ / 4);
  gemm_mfma256<1><<<dim3((BS_ / 256) * (DF_ / 256)), 512, 0, stream>>>(
      h2, w1b, g, BS_, DF_, D_, w1_scale, b1, GELU_SCALE);
  // 7.5 convert w2; 8. FFN2 + bias + final residual -> d_out (512 blocks)
  cvt_f32_bf16<<<(D_ * DF_ / 4 + 255) / 256, 256, 0, stream>>>(w2, w2b, D_ * DF_ / 4);
  gemm_mfma<2, 64, 128, float><<<dim3(D_ / 128, BS_ / 64), 256, 0, stream>>>(
      g, w2b, out, BS_, D_, DF_, w2_scale, b2, x2, SQRT_TAU, SQRT_1MT);
}